// Round 11
// baseline (121.973 us; speedup 1.0000x reference)
//
#include <hip/hip_runtime.h>
#include <hip/hip_bf16.h>

#define BB 1024
#define DD 256
#define NREL 42

typedef __attribute__((ext_vector_type(8))) short short8_t;
typedef __attribute__((ext_vector_type(4))) short short4_t;
typedef __attribute__((ext_vector_type(4))) float f32x4;
typedef __attribute__((ext_vector_type(4))) int   i32x4;

__device__ __forceinline__ unsigned short bf16_of(float f) {
    // round-to-nearest-even f32 -> bf16 (inputs are finite normals)
    unsigned u = __float_as_uint(f);
    return (unsigned short)((u + 0x7FFFu + ((u >> 16) & 1u)) >> 16);
}

// ---------------- K0: x -> bf16: fragment-major xfrag + transposed xbfT ----------
// xfrag layout: for 16-row j-group jg and K-step ks, lane l (l=0..63) holds
// bf16 x[jg*16 + (l&15)][ks*32 + (l>>4)*8 .. +8]  (the exact MFMA B fragment).
// Flat index: ((jg*8 + ks)*64 + l)*8 shorts -> a wave's B-fragment load is ONE
// fully-coalesced 1 KB global_load_dwordx4.
__global__ __launch_bounds__(256) void cvt_kernel(const float* __restrict__ x,
                                                  unsigned short* __restrict__ xfrag,
                                                  unsigned short* __restrict__ xbfT) {
    __shared__ unsigned short t[64][72];
    const int bj = blockIdx.x * 64;
    const int bd = blockIdx.y * 64;
    const int tid = threadIdx.x;
    const int tr = tid >> 4;
    const int tc = tid & 15;

    #pragma unroll
    for (int rr = 0; rr < 4; ++rr) {
        const int jl = rr * 16 + tr;
        const f32x4 v = *reinterpret_cast<const f32x4*>(&x[(bj + jl) * DD + bd + tc * 4]);
        short4_t h;
        #pragma unroll
        for (int e = 0; e < 4; ++e) h[e] = (short)bf16_of(v[e]);
        *reinterpret_cast<short4_t*>(&t[jl][tc * 4]) = h;
    }
    __syncthreads();

    // fragment-major writes: 64 rows x 8 d8-chunks = 512 chunks over 256 threads
    #pragma unroll
    for (int c = 0; c < 2; ++c) {
        const int idx = c * 256 + tid;
        const int jl  = idx & 63;
        const int d8  = (idx >> 6) * 8;
        const int j   = bj + jl, d = bd + d8;
        const int jg = j >> 4, lc = j & 15, ks = d >> 5, g2 = (d >> 3) & 3;
        const short8_t v = *reinterpret_cast<const short8_t*>(&t[jl][d8]);
        *reinterpret_cast<short8_t*>(
            &xfrag[(size_t)(((jg * 8 + ks) * 64) + g2 * 16 + lc) * 8]) = v;
    }

    // transposed copy for the output GEMM
    #pragma unroll
    for (int rr = 0; rr < 4; ++rr) {
        const int dl = rr * 16 + tr;
        short4_t h;
        #pragma unroll
        for (int e = 0; e < 4; ++e) h[e] = (short)t[tc * 4 + e][dl];
        *reinterpret_cast<short4_t*>(&xbfT[(bd + dl) * BB + bj + tc * 4]) = h;
    }
}

// ---------------- K1 (fused): logits GEMM + gather + softmax -> normalized P ----
// 1024 blocks x 256 thr (4 waves; 4 blocks/CU -> 16 waves/CU = 4/SIMD).
// Block = one row i. Wave w owns j-quarter w (16 subtiles of 16 j).
// A_i (48x256 bf16) in VGPRs. B fragments loaded DIRECTLY global->reg from
// fragment-major xfrag (1 KB coalesced per load, L2-resident), ping-pong
// buffered, NO LDS staging, NO barriers in the K-loop. Per 16-j subtile:
// 8 loads + 24 MFMA (3 acc chains). Epilogue gathers S[q[i,j], j]; pre-softmax
// barrier; per-wave full-row softmax writes its P quarter.
__global__ __launch_bounds__(256, 4) void attn_kernel(const float* __restrict__ x,
                                                      const int* __restrict__ q,
                                                      const float* __restrict__ R,
                                                      const unsigned short* __restrict__ xfrag,
                                                      unsigned short* __restrict__ P) {
    __shared__ float s_attn[BB];           // logit row for this i (4 KB)
    __shared__ unsigned short s_qs[BB];    // q row (2 KB, values < 42)

    const int tid  = threadIdx.x;
    const int w    = tid >> 6;       // 0..3: j-quarter
    const int lane = tid & 63;
    const int lcol = lane & 15;
    const int g    = lane >> 4;
    const int lk8  = g * 8;
    const int i    = blockIdx.x;

    // --- q row -> LDS (u16): 256 threads x 4 values ---
    {
        const int c4 = tid * 4;
        const i32x4 qa = *reinterpret_cast<const i32x4*>(&q[i * BB + c4]);
        short4_t sa;
        sa[0] = (short)qa[0]; sa[1] = (short)qa[1];
        sa[2] = (short)qa[2]; sa[3] = (short)qa[3];
        *reinterpret_cast<short4_t*>(&s_qs[c4]) = sa;
    }

    // --- A_i fragments in registers: afrag[mt*8+ks] = bf16(R[k][d]*x[i][d]) ---
    short8_t afrag[24];
    #pragma unroll
    for (int ks = 0; ks < 8; ++ks) {
        const int d0 = ks * 32 + lk8;
        const f32x4 x0 = *reinterpret_cast<const f32x4*>(&x[i * DD + d0]);
        const f32x4 x1 = *reinterpret_cast<const f32x4*>(&x[i * DD + d0 + 4]);
        #pragma unroll
        for (int mt = 0; mt < 3; ++mt) {
            const int k = mt * 16 + lcol;
            short8_t v = (short8_t)0;
            if (k < NREL) {
                const f32x4 r0 = *reinterpret_cast<const f32x4*>(&R[k * DD + d0]);
                const f32x4 r1 = *reinterpret_cast<const f32x4*>(&R[k * DD + d0 + 4]);
                #pragma unroll
                for (int e = 0; e < 4; ++e) {
                    v[e]     = (short)bf16_of(r0[e] * x0[e]);
                    v[e + 4] = (short)bf16_of(r1[e] * x1[e]);
                }
            }
            afrag[mt * 8 + ks] = v;
        }
    }

    __syncthreads();   // s_qs ready

    // Wave's B-fragment stream: subtile s covers j-group jg = w*16 + s.
    const unsigned short* fbase = xfrag + (size_t)(w * 16) * 4096 + lane * 8;

    short8_t ba[8], bb[8];

    auto loadb = [&](short8_t (&b)[8], int s_) {
        const unsigned short* base = fbase + (size_t)s_ * 4096;
        #pragma unroll
        for (int k = 0; k < 8; ++k)
            b[k] = *reinterpret_cast<const short8_t*>(base + k * 512);
    };
    auto computeb = [&](short8_t (&b)[8], int s_) {
        f32x4 a0 = (f32x4)0.0f, a1 = (f32x4)0.0f, a2 = (f32x4)0.0f;
        #pragma unroll
        for (int ks = 0; ks < 8; ++ks) {
            a0 = __builtin_amdgcn_mfma_f32_16x16x32_bf16(afrag[ks],      b[ks], a0, 0, 0, 0);
            a1 = __builtin_amdgcn_mfma_f32_16x16x32_bf16(afrag[8 + ks],  b[ks], a1, 0, 0, 0);
            a2 = __builtin_amdgcn_mfma_f32_16x16x32_bf16(afrag[16 + ks], b[ks], a2, 0, 0, 0);
        }
        // Exactly one lane per j holds S[q[i,j], j]: col=lcol, row=g*4+r.
        const int jl = (w * 16 + s_) * 16 + lcol;
        const int qv = (int)s_qs[jl];
        if (((qv >> 2) & 3) == g) {
            const int mt = qv >> 4;                       // 0..2 (qv < 42)
            const f32x4 av = (mt == 0) ? a0 : (mt == 1) ? a1 : a2;
            const float v = (qv & 2) ? ((qv & 1) ? av[3] : av[2])
                                     : ((qv & 1) ? av[1] : av[0]);
            s_attn[jl] = v;
        }
    };

    loadb(ba, 0);
    for (int s = 0; s < 16; s += 2) {
        loadb(bb, (s + 1 < 16) ? s + 1 : 15);   // prefetch next subtile
        computeb(ba, s);
        loadb(ba, (s + 2 < 16) ? s + 2 : 15);   // prefetch next-next
        computeb(bb, s + 1);
    }

    __syncthreads();   // s_attn complete

    // --- softmax: full-row reduce (redundant x4), write own P quarter ---
    f32x4 v4[4];
    #pragma unroll
    for (int kk = 0; kk < 4; ++kk)
        v4[kk] = *reinterpret_cast<const f32x4*>(&s_attn[kk * 256 + lane * 4]);

    float m = -1e30f;
    #pragma unroll
    for (int kk = 0; kk < 4; ++kk)
        m = fmaxf(m, fmaxf(fmaxf(v4[kk][0], v4[kk][1]), fmaxf(v4[kk][2], v4[kk][3])));
    #pragma unroll
    for (int off = 1; off < 64; off <<= 1) m = fmaxf(m, __shfl_xor(m, off));

    float e[16];
    float ssum = 0.f;
    #pragma unroll
    for (int kk = 0; kk < 4; ++kk)
        #pragma unroll
        for (int ee = 0; ee < 4; ++ee) {
            const float t2 = __expf(v4[kk][ee] - m);
            e[kk * 4 + ee] = t2;
            ssum += t2;
        }
    #pragma unroll
    for (int off = 1; off < 64; off <<= 1) ssum += __shfl_xor(ssum, off);
    const float inv = 1.0f / ssum;

    {
        short4_t pv;
        #pragma unroll
        for (int ee = 0; ee < 4; ++ee) pv[ee] = (short)bf16_of(e[w * 4 + ee] * inv);
        *reinterpret_cast<short4_t*>(&P[i * BB + w * 256 + lane * 4]) = pv;
    }
}

// ---------------- K3a: partial out GEMM, split-K z=4 -----------------------------
__global__ __launch_bounds__(256) void out_partial(const unsigned short* __restrict__ P,
                                                   const unsigned short* __restrict__ xbfT,
                                                   float* __restrict__ part) {
    const int tid = threadIdx.x;
    const int wave = tid >> 6, lane = tid & 63;
    const int lcol = lane & 15;
    const int lk8  = (lane >> 4) * 8;
    const int i0 = blockIdx.y * 64 + wave * 16;
    const int d0 = blockIdx.x * 64;
    const int k0 = blockIdx.z * 256;

    f32x4 acc[4];
    #pragma unroll
    for (int nt = 0; nt < 4; ++nt) acc[nt] = (f32x4)0.0f;

    #pragma unroll
    for (int ks = 0; ks < 8; ++ks) {
        const short8_t a = *reinterpret_cast<const short8_t*>(
            &P[(i0 + lcol) * BB + k0 + ks * 32 + lk8]);
        #pragma unroll
        for (int nt = 0; nt < 4; ++nt) {
            const short8_t b = *reinterpret_cast<const short8_t*>(
                &xbfT[(d0 + nt * 16 + lcol) * BB + k0 + ks * 32 + lk8]);
            acc[nt] = __builtin_amdgcn_mfma_f32_16x16x32_bf16(a, b, acc[nt], 0, 0, 0);
        }
    }

    const int rbase = (lane >> 4) * 4;
    float* pz = part + (size_t)blockIdx.z * BB * DD;
    #pragma unroll
    for (int r = 0; r < 4; ++r)
        #pragma unroll
        for (int nt = 0; nt < 4; ++nt)
            pz[(i0 + rbase + r) * DD + d0 + nt * 16 + lcol] = acc[nt][r];
}

// ---------------- K3b: out = sum_z part[z] (P already normalized) ---------------
__global__ __launch_bounds__(256) void out_reduce(const float* __restrict__ part,
                                                  float* __restrict__ out) {
    const int idx = blockIdx.x * DD + threadIdx.x;
    out[idx] = (part[idx] + part[BB * DD + idx]) +
               (part[2 * BB * DD + idx] + part[3 * BB * DD + idx]);
}

// ---------------- launch ---------------------------------------------------------
extern "C" void kernel_launch(void* const* d_in, const int* in_sizes, int n_in,
                              void* d_out, int out_size, void* d_ws, size_t ws_size,
                              hipStream_t stream) {
    (void)in_sizes; (void)n_in; (void)out_size; (void)ws_size;
    const float* x = (const float*)d_in[0];
    // d_in[1] = x_mask (unused), d_in[3] = f (unused)
    const int* q = (const int*)d_in[2];
    const float* R = (const float*)d_in[4];
    float* out = (float*)d_out;

    char* ws = (char*)d_ws;
    unsigned short* xfrag = (unsigned short*)(ws);                  // 512 KB
    unsigned short* xbfT  = (unsigned short*)(ws + (512u << 10));   // 512 KB
    unsigned short* P     = (unsigned short*)(ws + (1024u << 10));  // 2 MB
    float*          part  = (float*)(ws + (3072u << 10));           // 4 MB (z=4)

    cvt_kernel<<<dim3(16, 4), 256, 0, stream>>>(x, xfrag, xbfT);
    attn_kernel<<<dim3(BB), 256, 0, stream>>>(x, q, R, xfrag, P);
    out_partial<<<dim3(4, 16, 4), 256, 0, stream>>>(P, xbfT, part);
    out_reduce<<<dim3(BB), 256, 0, stream>>>(part, out);
}

// Round 12
// 62.740 us; speedup vs baseline: 1.9441x; 1.9441x over previous
//
#include <hip/hip_runtime.h>
#include <hip/hip_bf16.h>

#define BB 1024
#define DD 256
#define NREL 42

typedef __attribute__((ext_vector_type(8))) short short8_t;
typedef __attribute__((ext_vector_type(4))) short short4_t;
typedef __attribute__((ext_vector_type(4))) float f32x4;
typedef __attribute__((ext_vector_type(4))) int   i32x4;

__device__ __forceinline__ unsigned short bf16_of(float f) {
    // round-to-nearest-even f32 -> bf16 (inputs are finite normals)
    unsigned u = __float_as_uint(f);
    return (unsigned short)((u + 0x7FFFu + ((u >> 16) & 1u)) >> 16);
}

// ---------------- K0: x -> bf16: fragment-major xfrag + transposed xbfT ----------
// xfrag layout: for 16-row j-group jg and K-step ks, lane l (l=0..63) holds
// bf16 x[jg*16 + (l&15)][ks*32 + (l>>4)*8 .. +8]  (the exact MFMA B fragment).
// Flat index: ((jg*8 + ks)*64 + l)*8 shorts -> a wave's B-fragment load is ONE
// fully-coalesced 1 KB global_load_dwordx4.
__global__ __launch_bounds__(256) void cvt_kernel(const float* __restrict__ x,
                                                  unsigned short* __restrict__ xfrag,
                                                  unsigned short* __restrict__ xbfT) {
    __shared__ unsigned short t[64][72];
    const int bj = blockIdx.x * 64;
    const int bd = blockIdx.y * 64;
    const int tid = threadIdx.x;
    const int tr = tid >> 4;
    const int tc = tid & 15;

    #pragma unroll
    for (int rr = 0; rr < 4; ++rr) {
        const int jl = rr * 16 + tr;
        const f32x4 v = *reinterpret_cast<const f32x4*>(&x[(bj + jl) * DD + bd + tc * 4]);
        short4_t h;
        #pragma unroll
        for (int e = 0; e < 4; ++e) h[e] = (short)bf16_of(v[e]);
        *reinterpret_cast<short4_t*>(&t[jl][tc * 4]) = h;
    }
    __syncthreads();

    // fragment-major writes: 64 rows x 8 d8-chunks = 512 chunks over 256 threads
    #pragma unroll
    for (int c = 0; c < 2; ++c) {
        const int idx = c * 256 + tid;
        const int jl  = idx & 63;
        const int d8  = (idx >> 6) * 8;
        const int j   = bj + jl, d = bd + d8;
        const int jg = j >> 4, lc = j & 15, ks = d >> 5, g2 = (d >> 3) & 3;
        const short8_t v = *reinterpret_cast<const short8_t*>(&t[jl][d8]);
        *reinterpret_cast<short8_t*>(
            &xfrag[(size_t)(((jg * 8 + ks) * 64) + g2 * 16 + lc) * 8]) = v;
    }

    // transposed copy for the output GEMM
    #pragma unroll
    for (int rr = 0; rr < 4; ++rr) {
        const int dl = rr * 16 + tr;
        short4_t h;
        #pragma unroll
        for (int e = 0; e < 4; ++e) h[e] = (short)t[tc * 4 + e][dl];
        *reinterpret_cast<short4_t*>(&xbfT[(bd + dl) * BB + bj + tc * 4]) = h;
    }
}

// ---------------- K1 (fused): logits GEMM + gather + softmax -> normalized P ----
// 1024 blocks x 256 thr (4 waves). Block = one row i; wave w owns j-quarter w
// (16 subtiles of 16 j). NO second launch_bounds arg: r10/r11 proved it forces
// a 64-VGPR cap and spills the 160-reg working set to scratch. At the natural
// 128 VGPR the HW itself allows 16 waves/CU; the 1024-block grid supplies
// 4 blocks/CU -> 4 waves/SIMD with no compiler coercion.
// A_i (48x256 bf16) in VGPRs. B fragments loaded DIRECTLY global->reg from
// fragment-major xfrag (1 KB coalesced per load, L2-resident), ping-pong
// buffered, NO LDS staging, NO barriers in the K-loop. Per 16-j subtile:
// 8 loads + 24 MFMA (3 acc chains). Epilogue gathers S[q[i,j], j]; pre-softmax
// barrier; per-wave full-row softmax writes its P quarter.
__global__ __launch_bounds__(256) void attn_kernel(const float* __restrict__ x,
                                                   const int* __restrict__ q,
                                                   const float* __restrict__ R,
                                                   const unsigned short* __restrict__ xfrag,
                                                   unsigned short* __restrict__ P) {
    __shared__ float s_attn[BB];           // logit row for this i (4 KB)
    __shared__ unsigned short s_qs[BB];    // q row (2 KB, values < 42)

    const int tid  = threadIdx.x;
    const int w    = tid >> 6;       // 0..3: j-quarter
    const int lane = tid & 63;
    const int lcol = lane & 15;
    const int g    = lane >> 4;
    const int lk8  = g * 8;
    const int i    = blockIdx.x;

    // --- q row -> LDS (u16): 256 threads x 4 values ---
    {
        const int c4 = tid * 4;
        const i32x4 qa = *reinterpret_cast<const i32x4*>(&q[i * BB + c4]);
        short4_t sa;
        sa[0] = (short)qa[0]; sa[1] = (short)qa[1];
        sa[2] = (short)qa[2]; sa[3] = (short)qa[3];
        *reinterpret_cast<short4_t*>(&s_qs[c4]) = sa;
    }

    // --- A_i fragments in registers: afrag[mt*8+ks] = bf16(R[k][d]*x[i][d]) ---
    short8_t afrag[24];
    #pragma unroll
    for (int ks = 0; ks < 8; ++ks) {
        const int d0 = ks * 32 + lk8;
        const f32x4 x0 = *reinterpret_cast<const f32x4*>(&x[i * DD + d0]);
        const f32x4 x1 = *reinterpret_cast<const f32x4*>(&x[i * DD + d0 + 4]);
        #pragma unroll
        for (int mt = 0; mt < 3; ++mt) {
            const int k = mt * 16 + lcol;
            short8_t v = (short8_t)0;
            if (k < NREL) {
                const f32x4 r0 = *reinterpret_cast<const f32x4*>(&R[k * DD + d0]);
                const f32x4 r1 = *reinterpret_cast<const f32x4*>(&R[k * DD + d0 + 4]);
                #pragma unroll
                for (int e = 0; e < 4; ++e) {
                    v[e]     = (short)bf16_of(r0[e] * x0[e]);
                    v[e + 4] = (short)bf16_of(r1[e] * x1[e]);
                }
            }
            afrag[mt * 8 + ks] = v;
        }
    }

    __syncthreads();   // s_qs ready

    // Wave's B-fragment stream: subtile s covers j-group jg = w*16 + s.
    const unsigned short* fbase = xfrag + (size_t)(w * 16) * 4096 + lane * 8;

    short8_t ba[8], bb[8];

    auto loadb = [&](short8_t (&b)[8], int s_) {
        const unsigned short* base = fbase + (size_t)s_ * 4096;
        #pragma unroll
        for (int k = 0; k < 8; ++k)
            b[k] = *reinterpret_cast<const short8_t*>(base + k * 512);
    };
    auto computeb = [&](short8_t (&b)[8], int s_) {
        f32x4 a0 = (f32x4)0.0f, a1 = (f32x4)0.0f, a2 = (f32x4)0.0f;
        #pragma unroll
        for (int ks = 0; ks < 8; ++ks) {
            a0 = __builtin_amdgcn_mfma_f32_16x16x32_bf16(afrag[ks],      b[ks], a0, 0, 0, 0);
            a1 = __builtin_amdgcn_mfma_f32_16x16x32_bf16(afrag[8 + ks],  b[ks], a1, 0, 0, 0);
            a2 = __builtin_amdgcn_mfma_f32_16x16x32_bf16(afrag[16 + ks], b[ks], a2, 0, 0, 0);
        }
        // Exactly one lane per j holds S[q[i,j], j]: col=lcol, row=g*4+r.
        const int jl = (w * 16 + s_) * 16 + lcol;
        const int qv = (int)s_qs[jl];
        if (((qv >> 2) & 3) == g) {
            const int mt = qv >> 4;                       // 0..2 (qv < 42)
            const f32x4 av = (mt == 0) ? a0 : (mt == 1) ? a1 : a2;
            const float v = (qv & 2) ? ((qv & 1) ? av[3] : av[2])
                                     : ((qv & 1) ? av[1] : av[0]);
            s_attn[jl] = v;
        }
    };

    loadb(ba, 0);
    for (int s = 0; s < 16; s += 2) {
        loadb(bb, (s + 1 < 16) ? s + 1 : 15);   // prefetch next subtile
        computeb(ba, s);
        loadb(ba, (s + 2 < 16) ? s + 2 : 15);   // prefetch next-next
        computeb(bb, s + 1);
    }

    __syncthreads();   // s_attn complete

    // --- softmax: full-row reduce (redundant x4), write own P quarter ---
    f32x4 v4[4];
    #pragma unroll
    for (int kk = 0; kk < 4; ++kk)
        v4[kk] = *reinterpret_cast<const f32x4*>(&s_attn[kk * 256 + lane * 4]);

    float m = -1e30f;
    #pragma unroll
    for (int kk = 0; kk < 4; ++kk)
        m = fmaxf(m, fmaxf(fmaxf(v4[kk][0], v4[kk][1]), fmaxf(v4[kk][2], v4[kk][3])));
    #pragma unroll
    for (int off = 1; off < 64; off <<= 1) m = fmaxf(m, __shfl_xor(m, off));

    float e[16];
    float ssum = 0.f;
    #pragma unroll
    for (int kk = 0; kk < 4; ++kk)
        #pragma unroll
        for (int ee = 0; ee < 4; ++ee) {
            const float t2 = __expf(v4[kk][ee] - m);
            e[kk * 4 + ee] = t2;
            ssum += t2;
        }
    #pragma unroll
    for (int off = 1; off < 64; off <<= 1) ssum += __shfl_xor(ssum, off);
    const float inv = 1.0f / ssum;

    {
        short4_t pv;
        #pragma unroll
        for (int ee = 0; ee < 4; ++ee) pv[ee] = (short)bf16_of(e[w * 4 + ee] * inv);
        *reinterpret_cast<short4_t*>(&P[i * BB + w * 256 + lane * 4]) = pv;
    }
}

// ---------------- K3a: partial out GEMM, split-K z=4 -----------------------------
__global__ __launch_bounds__(256) void out_partial(const unsigned short* __restrict__ P,
                                                   const unsigned short* __restrict__ xbfT,
                                                   float* __restrict__ part) {
    const int tid = threadIdx.x;
    const int wave = tid >> 6, lane = tid & 63;
    const int lcol = lane & 15;
    const int lk8  = (lane >> 4) * 8;
    const int i0 = blockIdx.y * 64 + wave * 16;
    const int d0 = blockIdx.x * 64;
    const int k0 = blockIdx.z * 256;

    f32x4 acc[4];
    #pragma unroll
    for (int nt = 0; nt < 4; ++nt) acc[nt] = (f32x4)0.0f;

    #pragma unroll
    for (int ks = 0; ks < 8; ++ks) {
        const short8_t a = *reinterpret_cast<const short8_t*>(
            &P[(i0 + lcol) * BB + k0 + ks * 32 + lk8]);
        #pragma unroll
        for (int nt = 0; nt < 4; ++nt) {
            const short8_t b = *reinterpret_cast<const short8_t*>(
                &xbfT[(d0 + nt * 16 + lcol) * BB + k0 + ks * 32 + lk8]);
            acc[nt] = __builtin_amdgcn_mfma_f32_16x16x32_bf16(a, b, acc[nt], 0, 0, 0);
        }
    }

    const int rbase = (lane >> 4) * 4;
    float* pz = part + (size_t)blockIdx.z * BB * DD;
    #pragma unroll
    for (int r = 0; r < 4; ++r)
        #pragma unroll
        for (int nt = 0; nt < 4; ++nt)
            pz[(i0 + rbase + r) * DD + d0 + nt * 16 + lcol] = acc[nt][r];
}

// ---------------- K3b: out = sum_z part[z] (P already normalized) ---------------
__global__ __launch_bounds__(256) void out_reduce(const float* __restrict__ part,
                                                  float* __restrict__ out) {
    const int idx = blockIdx.x * DD + threadIdx.x;
    out[idx] = (part[idx] + part[BB * DD + idx]) +
               (part[2 * BB * DD + idx] + part[3 * BB * DD + idx]);
}

// ---------------- launch ---------------------------------------------------------
extern "C" void kernel_launch(void* const* d_in, const int* in_sizes, int n_in,
                              void* d_out, int out_size, void* d_ws, size_t ws_size,
                              hipStream_t stream) {
    (void)in_sizes; (void)n_in; (void)out_size; (void)ws_size;
    const float* x = (const float*)d_in[0];
    // d_in[1] = x_mask (unused), d_in[3] = f (unused)
    const int* q = (const int*)d_in[2];
    const float* R = (const float*)d_in[4];
    float* out = (float*)d_out;

    char* ws = (char*)d_ws;
    unsigned short* xfrag = (unsigned short*)(ws);                  // 512 KB
    unsigned short* xbfT  = (unsigned short*)(ws + (512u << 10));   // 512 KB
    unsigned short* P     = (unsigned short*)(ws + (1024u << 10));  // 2 MB
    float*          part  = (float*)(ws + (3072u << 10));           // 4 MB (z=4)

    cvt_kernel<<<dim3(16, 4), 256, 0, stream>>>(x, xfrag, xbfT);
    attn_kernel<<<dim3(BB), 256, 0, stream>>>(x, q, R, xfrag, P);
    out_partial<<<dim3(4, 16, 4), 256, 0, stream>>>(P, xbfT, part);
    out_reduce<<<dim3(BB), 256, 0, stream>>>(part, out);
}

// Round 13
// 59.738 us; speedup vs baseline: 2.0418x; 1.0502x over previous
//
#include <hip/hip_runtime.h>
#include <hip/hip_bf16.h>

#define BB 1024
#define DD 256
#define NREL 42

typedef __attribute__((ext_vector_type(8))) short short8_t;
typedef __attribute__((ext_vector_type(4))) short short4_t;
typedef __attribute__((ext_vector_type(4))) float f32x4;
typedef __attribute__((ext_vector_type(4))) int   i32x4;

__device__ __forceinline__ unsigned short bf16_of(float f) {
    // round-to-nearest-even f32 -> bf16 (inputs are finite normals)
    unsigned u = __float_as_uint(f);
    return (unsigned short)((u + 0x7FFFu + ((u >> 16) & 1u)) >> 16);
}

// ---------------- K0: x -> bf16: fragment-major xfrag + transposed xbfT ----------
// xfrag layout: for 16-row j-group jg and K-step ks, lane l (l=0..63) holds
// bf16 x[jg*16 + (l&15)][ks*32 + (l>>4)*8 .. +8]  (the exact MFMA B fragment).
// Flat index: ((jg*8 + ks)*64 + l)*8 shorts -> a wave's B-fragment load is ONE
// fully-coalesced 1 KB global_load_dwordx4.
__global__ __launch_bounds__(256) void cvt_kernel(const float* __restrict__ x,
                                                  unsigned short* __restrict__ xfrag,
                                                  unsigned short* __restrict__ xbfT) {
    __shared__ unsigned short t[64][72];
    const int bj = blockIdx.x * 64;
    const int bd = blockIdx.y * 64;
    const int tid = threadIdx.x;
    const int tr = tid >> 4;
    const int tc = tid & 15;

    #pragma unroll
    for (int rr = 0; rr < 4; ++rr) {
        const int jl = rr * 16 + tr;
        const f32x4 v = *reinterpret_cast<const f32x4*>(&x[(bj + jl) * DD + bd + tc * 4]);
        short4_t h;
        #pragma unroll
        for (int e = 0; e < 4; ++e) h[e] = (short)bf16_of(v[e]);
        *reinterpret_cast<short4_t*>(&t[jl][tc * 4]) = h;
    }
    __syncthreads();

    // fragment-major writes: 64 rows x 8 d8-chunks = 512 chunks over 256 threads
    #pragma unroll
    for (int c = 0; c < 2; ++c) {
        const int idx = c * 256 + tid;
        const int jl  = idx & 63;
        const int d8  = (idx >> 6) * 8;
        const int j   = bj + jl, d = bd + d8;
        const int jg = j >> 4, lc = j & 15, ks = d >> 5, g2 = (d >> 3) & 3;
        const short8_t v = *reinterpret_cast<const short8_t*>(&t[jl][d8]);
        *reinterpret_cast<short8_t*>(
            &xfrag[(size_t)(((jg * 8 + ks) * 64) + g2 * 16 + lc) * 8]) = v;
    }

    // transposed copy for the output GEMM
    #pragma unroll
    for (int rr = 0; rr < 4; ++rr) {
        const int dl = rr * 16 + tr;
        short4_t h;
        #pragma unroll
        for (int e = 0; e < 4; ++e) h[e] = (short)t[tc * 4 + e][dl];
        *reinterpret_cast<short4_t*>(&xbfT[(bd + dl) * BB + bj + tc * 4]) = h;
    }
}

// ---------------- K1 (fused): logits GEMM + gather + softmax -> normalized P ----
// r9 structure (best known: 43 us), ONE change: 4-buffer B pipeline (3-subtile
// lookahead ~1900 cyc) instead of 2-buffer (1-subtile ~600 cyc), to cover the
// contended L2 latency that r9's counters showed dominating (~3200 cyc/subtile
// vs ~500 cyc of work).
// 512 blocks x 256 thr (4 waves). Wave w: p=w&1 -> row i=blk*2+p; jh=w>>1 ->
// j-half (32 subtiles of 16 j). Wave pairs (same jh, diff p) share the B-load
// stream -> L1 hits keep L2 traffic at 256 MB. A_i (48x256 bf16) in VGPRs.
// B fragments direct global->reg from fragment-major xfrag (1 KB coalesced per
// load), NO LDS staging, NO K-loop barriers. Epilogue gathers S[q[i,j], j];
// per-wave full-row softmax writes its P half.
__global__ __launch_bounds__(256) void attn_kernel(const float* __restrict__ x,
                                                   const int* __restrict__ q,
                                                   const float* __restrict__ R,
                                                   const unsigned short* __restrict__ xfrag,
                                                   unsigned short* __restrict__ P) {
    __shared__ float s_attn[2][BB];           // per-i logit row (8 KB)
    __shared__ unsigned short s_qs[2][BB];    // per-i q row (4 KB)

    const int tid  = threadIdx.x;
    const int w    = tid >> 6;       // 0..3
    const int lane = tid & 63;
    const int p    = w & 1;          // which i this wave serves
    const int jh   = w >> 1;         // which 512-j half
    const int lcol = lane & 15;
    const int g    = lane >> 4;
    const int lk8  = g * 8;
    const int i    = blockIdx.x * 2 + p;

    // --- q rows -> LDS (u16): 2 rows x 1024 over 256 threads, 8 each ---
    {
        const int r  = tid >> 7;
        const int c8 = (tid & 127) * 8;
        const int qi = blockIdx.x * 2 + r;
        const i32x4 qa = *reinterpret_cast<const i32x4*>(&q[qi * BB + c8]);
        const i32x4 qb = *reinterpret_cast<const i32x4*>(&q[qi * BB + c8 + 4]);
        short4_t sa, sb;
        sa[0] = (short)qa[0]; sa[1] = (short)qa[1]; sa[2] = (short)qa[2]; sa[3] = (short)qa[3];
        sb[0] = (short)qb[0]; sb[1] = (short)qb[1]; sb[2] = (short)qb[2]; sb[3] = (short)qb[3];
        *reinterpret_cast<short4_t*>(&s_qs[r][c8])     = sa;
        *reinterpret_cast<short4_t*>(&s_qs[r][c8 + 4]) = sb;
    }

    // --- A_i fragments in registers: afrag[mt*8+ks] = bf16(R[k][d]*x[i][d]) ---
    short8_t afrag[24];
    #pragma unroll
    for (int ks = 0; ks < 8; ++ks) {
        const int d0 = ks * 32 + lk8;
        const f32x4 x0 = *reinterpret_cast<const f32x4*>(&x[i * DD + d0]);
        const f32x4 x1 = *reinterpret_cast<const f32x4*>(&x[i * DD + d0 + 4]);
        #pragma unroll
        for (int mt = 0; mt < 3; ++mt) {
            const int k = mt * 16 + lcol;
            short8_t v = (short8_t)0;
            if (k < NREL) {
                const f32x4 r0 = *reinterpret_cast<const f32x4*>(&R[k * DD + d0]);
                const f32x4 r1 = *reinterpret_cast<const f32x4*>(&R[k * DD + d0 + 4]);
                #pragma unroll
                for (int e = 0; e < 4; ++e) {
                    v[e]     = (short)bf16_of(r0[e] * x0[e]);
                    v[e + 4] = (short)bf16_of(r1[e] * x1[e]);
                }
            }
            afrag[mt * 8 + ks] = v;
        }
    }

    __syncthreads();   // s_qs ready

    // Wave's B-fragment stream: subtile s covers j-group jg = jh*32 + s.
    const unsigned short* fbase = xfrag + (size_t)(jh * 32) * 4096 + lane * 8;

    short8_t b0[8], b1[8], b2[8], b3[8];

    auto loadb = [&](short8_t (&b)[8], int s_) {
        const int sc = (s_ < 32) ? s_ : 31;
        const unsigned short* base = fbase + (size_t)sc * 4096;
        #pragma unroll
        for (int k = 0; k < 8; ++k)
            b[k] = *reinterpret_cast<const short8_t*>(base + k * 512);
    };
    auto computeb = [&](short8_t (&b)[8], int s_) {
        f32x4 a0 = (f32x4)0.0f, a1 = (f32x4)0.0f, a2 = (f32x4)0.0f;
        #pragma unroll
        for (int ks = 0; ks < 8; ++ks) {
            a0 = __builtin_amdgcn_mfma_f32_16x16x32_bf16(afrag[ks],      b[ks], a0, 0, 0, 0);
            a1 = __builtin_amdgcn_mfma_f32_16x16x32_bf16(afrag[8 + ks],  b[ks], a1, 0, 0, 0);
            a2 = __builtin_amdgcn_mfma_f32_16x16x32_bf16(afrag[16 + ks], b[ks], a2, 0, 0, 0);
        }
        // Exactly one lane per j holds S[q[i,j], j]: col=lcol, row=g*4+r.
        const int jl = (jh * 32 + s_) * 16 + lcol;
        const int qv = (int)s_qs[p][jl];
        if (((qv >> 2) & 3) == g) {
            const int mt = qv >> 4;                       // 0..2 (qv < 42)
            const f32x4 av = (mt == 0) ? a0 : (mt == 1) ? a1 : a2;
            const float v = (qv & 2) ? ((qv & 1) ? av[3] : av[2])
                                     : ((qv & 1) ? av[1] : av[0]);
            s_attn[p][jl] = v;
        }
    };

    // 4-buffer pipeline: 3 subtiles always in flight ahead of the consumer.
    loadb(b0, 0);
    loadb(b1, 1);
    loadb(b2, 2);
    for (int s = 0; s < 32; s += 4) {
        loadb(b3, s + 3);  computeb(b0, s);
        loadb(b0, s + 4);  computeb(b1, s + 1);
        loadb(b1, s + 5);  computeb(b2, s + 2);
        loadb(b2, s + 6);  computeb(b3, s + 3);
    }

    __syncthreads();   // s_attn complete

    // --- softmax: full-row reduce (redundant in wave pair), write own P half ---
    f32x4 v4[4];
    #pragma unroll
    for (int kk = 0; kk < 4; ++kk)
        v4[kk] = *reinterpret_cast<const f32x4*>(&s_attn[p][kk * 256 + lane * 4]);

    float m = -1e30f;
    #pragma unroll
    for (int kk = 0; kk < 4; ++kk)
        m = fmaxf(m, fmaxf(fmaxf(v4[kk][0], v4[kk][1]), fmaxf(v4[kk][2], v4[kk][3])));
    #pragma unroll
    for (int off = 1; off < 64; off <<= 1) m = fmaxf(m, __shfl_xor(m, off));

    float e[16];
    float ssum = 0.f;
    #pragma unroll
    for (int kk = 0; kk < 4; ++kk)
        #pragma unroll
        for (int ee = 0; ee < 4; ++ee) {
            const float t2 = __expf(v4[kk][ee] - m);
            e[kk * 4 + ee] = t2;
            ssum += t2;
        }
    #pragma unroll
    for (int off = 1; off < 64; off <<= 1) ssum += __shfl_xor(ssum, off);
    const float inv = 1.0f / ssum;

    #pragma unroll
    for (int kk2 = 0; kk2 < 2; ++kk2) {
        const int kk = jh * 2 + kk2;
        short4_t pv;
        #pragma unroll
        for (int ee = 0; ee < 4; ++ee) pv[ee] = (short)bf16_of(e[kk * 4 + ee] * inv);
        *reinterpret_cast<short4_t*>(&P[i * BB + kk * 256 + lane * 4]) = pv;
    }
}

// ---------------- K3a: partial out GEMM, split-K z=4 -----------------------------
__global__ __launch_bounds__(256) void out_partial(const unsigned short* __restrict__ P,
                                                   const unsigned short* __restrict__ xbfT,
                                                   float* __restrict__ part) {
    const int tid = threadIdx.x;
    const int wave = tid >> 6, lane = tid & 63;
    const int lcol = lane & 15;
    const int lk8  = (lane >> 4) * 8;
    const int i0 = blockIdx.y * 64 + wave * 16;
    const int d0 = blockIdx.x * 64;
    const int k0 = blockIdx.z * 256;

    f32x4 acc[4];
    #pragma unroll
    for (int nt = 0; nt < 4; ++nt) acc[nt] = (f32x4)0.0f;

    #pragma unroll
    for (int ks = 0; ks < 8; ++ks) {
        const short8_t a = *reinterpret_cast<const short8_t*>(
            &P[(i0 + lcol) * BB + k0 + ks * 32 + lk8]);
        #pragma unroll
        for (int nt = 0; nt < 4; ++nt) {
            const short8_t b = *reinterpret_cast<const short8_t*>(
                &xbfT[(d0 + nt * 16 + lcol) * BB + k0 + ks * 32 + lk8]);
            acc[nt] = __builtin_amdgcn_mfma_f32_16x16x32_bf16(a, b, acc[nt], 0, 0, 0);
        }
    }

    const int rbase = (lane >> 4) * 4;
    float* pz = part + (size_t)blockIdx.z * BB * DD;
    #pragma unroll
    for (int r = 0; r < 4; ++r)
        #pragma unroll
        for (int nt = 0; nt < 4; ++nt)
            pz[(i0 + rbase + r) * DD + d0 + nt * 16 + lcol] = acc[nt][r];
}

// ---------------- K3b: out = sum_z part[z] (P already normalized) ---------------
__global__ __launch_bounds__(256) void out_reduce(const float* __restrict__ part,
                                                  float* __restrict__ out) {
    const int idx = blockIdx.x * DD + threadIdx.x;
    out[idx] = (part[idx] + part[BB * DD + idx]) +
               (part[2 * BB * DD + idx] + part[3 * BB * DD + idx]);
}

// ---------------- launch ---------------------------------------------------------
extern "C" void kernel_launch(void* const* d_in, const int* in_sizes, int n_in,
                              void* d_out, int out_size, void* d_ws, size_t ws_size,
                              hipStream_t stream) {
    (void)in_sizes; (void)n_in; (void)out_size; (void)ws_size;
    const float* x = (const float*)d_in[0];
    // d_in[1] = x_mask (unused), d_in[3] = f (unused)
    const int* q = (const int*)d_in[2];
    const float* R = (const float*)d_in[4];
    float* out = (float*)d_out;

    char* ws = (char*)d_ws;
    unsigned short* xfrag = (unsigned short*)(ws);                  // 512 KB
    unsigned short* xbfT  = (unsigned short*)(ws + (512u << 10));   // 512 KB
    unsigned short* P     = (unsigned short*)(ws + (1024u << 10));  // 2 MB
    float*          part  = (float*)(ws + (3072u << 10));           // 4 MB (z=4)

    cvt_kernel<<<dim3(16, 4), 256, 0, stream>>>(x, xfrag, xbfT);
    attn_kernel<<<dim3(512), 256, 0, stream>>>(x, q, R, xfrag, P);
    out_partial<<<dim3(4, 16, 4), 256, 0, stream>>>(P, xbfT, part);
    out_reduce<<<dim3(BB), 256, 0, stream>>>(part, out);
}